// Round 7
// baseline (513.145 us; speedup 1.0000x reference)
//
#include <hip/hip_runtime.h>

typedef __attribute__((ext_vector_type(8))) short short8;
typedef __attribute__((ext_vector_type(4))) float f32x4;
typedef __attribute__((ext_vector_type(4))) unsigned short u16x4;
typedef __attribute__((ext_vector_type(8))) unsigned short u16x8;

#define H 112
#define W 112
#define HP 114
#define WP 114
#define CIN 128
#define COUT 256
#define NPIX (H * W)          // 12544
#define NIMG 32
#define MTOT (NIMG * NPIX)    // 401408
#define PADELEMS ((long)NIMG * HP * WP * CIN)  // 53,231,616
#define NSTEP 36              // K-steps: 9 taps x 4 cin-chunks of 32

__device__ __forceinline__ unsigned short f2bf(float f) {
    unsigned int u = __builtin_bit_cast(unsigned int, f);
    u += 0x7FFFu + ((u >> 16) & 1u);
    return (unsigned short)(u >> 16);
}

__device__ __forceinline__ void gl2lds16(const void* g, void* l) {
    __builtin_amdgcn_global_load_lds(
        (const __attribute__((address_space(1))) unsigned int*)g,
        (__attribute__((address_space(3))) unsigned int*)l,
        16, 0, 0);
}

// ---- weights: bf16 {+1,-1}, layout [tap][kc4][cout][cin32] (R1 layout) ----
__global__ void binw_kernel(const float* __restrict__ kw, unsigned short* __restrict__ bw) {
    int tid = blockIdx.x * 256 + threadIdx.x;
    int cin5 = tid & 31;
    int cout = (tid >> 5) & 255;
    int kc4  = (tid >> 13) & 3;
    int tap  = tid >> 15;
    int cin  = kc4 * 32 + cin5;
    float w = kw[(tap * 128 + cin) * 256 + cout];
    bw[tid] = (w >= 0.0f) ? (unsigned short)0x3F80u : (unsigned short)0xBF80u;
}

// ---- x (f32 NHWC) -> zero-padded bf16 [N][114][114][128] ----
__global__ void pad_kernel(const float* __restrict__ x, unsigned short* __restrict__ xp) {
    long tid = (long)blockIdx.x * 256 + threadIdx.x;   // one thread = 8 elems
    if (tid >= PADELEMS / 8) return;
    int c8 = (int)(tid & 15);
    long rem = tid >> 4;
    int wp = (int)(rem % WP); rem /= WP;
    int hp = (int)(rem % HP);
    int n  = (int)(rem / HP);
    u16x8 v = {0, 0, 0, 0, 0, 0, 0, 0};
    if (hp >= 1 && hp <= H && wp >= 1 && wp <= W) {
        const float* s = x + (((long)(n * H + hp - 1) * W + (wp - 1)) * CIN + c8 * 8);
        f32x4 a = *(const f32x4*)s;
        f32x4 b = *(const f32x4*)(s + 4);
        v = (u16x8){ f2bf(a.x), f2bf(a.y), f2bf(a.z), f2bf(a.w),
                     f2bf(b.x), f2bf(b.y), f2bf(b.z), f2bf(b.w) };
    }
    *(u16x8*)(xp + tid * 8) = v;
}

// ---- 256x256 implicit GEMM, BK=32, 4-deep LDS ring, plane-major layout ----
// 8 waves (2M x 4N). Stage step t+2 while computing t: ~3 phases of load slack.
__global__ __launch_bounds__(512, 2)
void conv7_kernel(const unsigned short* __restrict__ xp, const unsigned short* __restrict__ bw,
                  float* __restrict__ out) {
    // [buf][plane(c=cin-chunk,4)][row(256)][8 shorts] : frag reads are 16-lane
    // contiguous 256B runs -> conflict-free, single base + imm offsets.
    __shared__ unsigned short As[4][8192];  // 4 x 16KB
    __shared__ unsigned short Bs[4][8192];  // 4 x 16KB

    const int tid = threadIdx.x;
    const int bm = (blockIdx.x & 7) * 196 + (blockIdx.x >> 3);  // XCD swizzle, 1568=8*196
    const int lane = tid & 63;
    const int wv = tid >> 6;
    const int wr = wv >> 2;   // 0..1
    const int wc = wv & 3;    // 0..3

    // ---- staging coords: thread -> (plane sc / sc+2, row srow), 16B each ----
    const int srow = tid & 255;
    const int sc = tid >> 8;   // 0/1
    {
        // nothing
    }
    int p = bm * 256 + srow;
    int n0 = p / NPIX;
    int rem0 = p - n0 * NPIX;
    int oh0 = rem0 / W, ow0 = rem0 - oh0 * W;
    const unsigned short* aptr = xp + (long)((n0 * HP + oh0 + 1) * WP + ow0 + 1) * CIN + sc * 8;
    const unsigned short* bptr = bw + srow * 32 + sc * 8;

    // per-step constants (compile-time in unrolled loop):
#define ASHIFT(T) (((((T) >> 2) / 3 - 1) * WP + (((T) >> 2) % 3 - 1)) * CIN + ((T) & 3) * 32)
#define STAGE(T, BUF, HALF) do {                                                \
        gl2lds16(aptr + ASHIFT(T) + (HALF) * 16,                                \
                 &As[BUF][(sc + (HALF) * 2) * 2048 + srow * 8]);                \
        gl2lds16(bptr + (T) * 8192 + (HALF) * 16,                               \
                 &Bs[BUF][(sc + (HALF) * 2) * 2048 + srow * 8]);                \
    } while (0)

    // ---- fragment read bases (shorts) ----
    const int l15 = lane & 15;
    const int lcp = (lane >> 4) * 2048;              // cin-chunk plane
    const int aoff = lcp + (wr * 128 + l15) * 8;     // + m*128
    const int boff = lcp + (wc * 64 + l15) * 8;      // + n*128

    f32x4 acc[8][4];
#pragma unroll
    for (int m = 0; m < 8; ++m)
#pragma unroll
        for (int nn = 0; nn < 4; ++nn)
            acc[m][nn] = (f32x4){0.f, 0.f, 0.f, 0.f};

    // prologue: steps 0,1 fully in flight (8 loads)
    STAGE(0, 0, 0); STAGE(0, 0, 1);
    STAGE(1, 1, 0); STAGE(1, 1, 1);

#pragma unroll
    for (int t = 0; t < NSTEP; ++t) {
        const int buf = t & 3;
        const int Tn = (t + 2) % NSTEP;     // wrap tail: dummy re-stage into dead bufs
        const int bufn = (t + 2) & 3;

        STAGE(Tn, bufn, 0);                  // 2 loads
        asm volatile("s_waitcnt vmcnt(6)" ::: "memory");   // step t resident (4 retired)
        __builtin_amdgcn_s_barrier();

        short8 bfr[4], afr[4];
#pragma unroll
        for (int nn = 0; nn < 4; ++nn)
            bfr[nn] = *(const short8*)&Bs[buf][boff + nn * 128];
#pragma unroll
        for (int m = 0; m < 4; ++m)
            afr[m] = *(const short8*)&As[buf][aoff + m * 128];
        asm volatile("s_waitcnt lgkmcnt(0)" ::: "memory");
        __builtin_amdgcn_sched_barrier(0);
        __builtin_amdgcn_s_setprio(1);
#pragma unroll
        for (int m = 0; m < 4; ++m)
#pragma unroll
            for (int nn = 0; nn < 4; ++nn)
                acc[m][nn] = __builtin_amdgcn_mfma_f32_16x16x32_bf16(
                    afr[m], bfr[nn], acc[m][nn], 0, 0, 0);
        __builtin_amdgcn_s_setprio(0);

        short8 afr2[4];
#pragma unroll
        for (int m = 0; m < 4; ++m)
            afr2[m] = *(const short8*)&As[buf][aoff + (4 + m) * 128];
        STAGE(Tn, bufn, 1);                  // 2 loads
        asm volatile("s_waitcnt lgkmcnt(0)" ::: "memory");
        __builtin_amdgcn_sched_barrier(0);
        __builtin_amdgcn_s_setprio(1);
#pragma unroll
        for (int m = 0; m < 4; ++m)
#pragma unroll
            for (int nn = 0; nn < 4; ++nn)
                acc[4 + m][nn] = __builtin_amdgcn_mfma_f32_16x16x32_bf16(
                    afr2[m], bfr[nn], acc[4 + m][nn], 0, 0, 0);
        __builtin_amdgcn_s_setprio(0);
        __builtin_amdgcn_s_barrier();
    }
#undef STAGE
#undef ASHIFT

    asm volatile("s_waitcnt vmcnt(0)" ::: "memory");  // drain wrap-around dummies
    __builtin_amdgcn_s_barrier();

    // ---- epilogue: C/D layout col=lane&15, row=(lane>>4)*4+j ----
    const long row0 = (long)bm * 256 + wr * 128 + (lane >> 4) * 4;
    const int col = wc * 64 + l15;
#pragma unroll
    for (int m = 0; m < 8; ++m)
#pragma unroll
        for (int nn = 0; nn < 4; ++nn)
#pragma unroll
            for (int j = 0; j < 4; ++j)
                out[(row0 + m * 16 + j) * COUT + col + nn * 16] = acc[m][nn][j];
}

// ---------------- fallback (round-1) path: needs no big workspace ----------------
__global__ __launch_bounds__(256, 2)
void conv_fallback_kernel(const float* __restrict__ x, const unsigned short* __restrict__ bw,
                          float* __restrict__ out) {
    __shared__ unsigned short As[128][40];
    __shared__ unsigned short Bs[128][40];
    const int tid = threadIdx.x;
    const int bm = blockIdx.x, bn = blockIdx.y;
    const int lane = tid & 63;
    const int wv = tid >> 6;
    const int wr = wv >> 1, wc = wv & 1;
    const int c4 = (tid & 7) * 4;
    const int rseg = tid >> 3;
    int ohs[4], ows[4], bases[4];
#pragma unroll
    for (int i = 0; i < 4; ++i) {
        int p = bm * 128 + rseg + i * 32;
        int n = p / NPIX;
        int rem = p - n * NPIX;
        int oh = rem / W, ow = rem - oh * W;
        ohs[i] = oh; ows[i] = ow;
        bases[i] = ((n * H + oh) * W + ow) * CIN;
    }
    f32x4 acc[4][4];
#pragma unroll
    for (int m = 0; m < 4; ++m)
#pragma unroll
        for (int n = 0; n < 4; ++n)
            acc[m][n] = (f32x4){0.f, 0.f, 0.f, 0.f};
    const int arow = wr * 64 + (lane & 15);
    const int brow = wc * 64 + (lane & 15);
    const int koff = (lane >> 4) * 8;
    for (int tap = 0; tap < 9; ++tap) {
        const int dh = tap / 3 - 1, dw = tap % 3 - 1;
        const int shift = (dh * W + dw) * CIN;
#pragma unroll
        for (int kc = 0; kc < 4; ++kc) {
            __syncthreads();
#pragma unroll
            for (int i = 0; i < 4; ++i) {
                int ih = ohs[i] + dh, iw = ows[i] + dw;
                bool valid = ((unsigned)ih < (unsigned)H) & ((unsigned)iw < (unsigned)W);
                f32x4 v = {0.f, 0.f, 0.f, 0.f};
                if (valid) v = *(const f32x4*)(x + bases[i] + shift + kc * 32 + c4);
                u16x4 s = { f2bf(v.x), f2bf(v.y), f2bf(v.z), f2bf(v.w) };
                *(u16x4*)&As[rseg + i * 32][c4] = s;
            }
            const unsigned short* bp = bw + tap * 32768 + kc * 8192 + bn * 4096;
#pragma unroll
            for (int j = 0; j < 2; ++j) {
                int idx = tid + j * 256;
                *(u16x8*)&Bs[idx >> 2][(idx & 3) * 8] = *(const u16x8*)(bp + (idx >> 2) * 32 + (idx & 3) * 8);
            }
            __syncthreads();
            short8 af[4], bfr[4];
#pragma unroll
            for (int m = 0; m < 4; ++m)
                af[m] = *(const short8*)&As[arow + m * 16][koff];
#pragma unroll
            for (int n = 0; n < 4; ++n)
                bfr[n] = *(const short8*)&Bs[brow + n * 16][koff];
#pragma unroll
            for (int m = 0; m < 4; ++m)
#pragma unroll
                for (int n = 0; n < 4; ++n)
                    acc[m][n] = __builtin_amdgcn_mfma_f32_16x16x32_bf16(af[m], bfr[n], acc[m][n], 0, 0, 0);
        }
    }
    const long row0 = (long)bm * 128 + wr * 64 + ((lane >> 4) * 4);
    const int col = bn * 128 + wc * 64 + (lane & 15);
#pragma unroll
    for (int m = 0; m < 4; ++m)
#pragma unroll
        for (int n = 0; n < 4; ++n)
#pragma unroll
            for (int j = 0; j < 4; ++j)
                out[(row0 + m * 16 + j) * COUT + col + n * 16] = acc[m][n][j];
}

extern "C" void kernel_launch(void* const* d_in, const int* in_sizes, int n_in,
                              void* d_out, int out_size, void* d_ws, size_t ws_size,
                              hipStream_t stream) {
    const float* x  = (const float*)d_in[0];
    const float* kw = (const float*)d_in[1];
    float* out = (float*)d_out;
    unsigned short* bw = (unsigned short*)d_ws;
    const size_t BW_BYTES = 9 * 4 * 256 * 32 * 2;         // 589,824
    const size_t PAD_BYTES = (size_t)PADELEMS * 2;        // ~106.5 MB

    binw_kernel<<<(9 * 256 * 128) / 256, 256, 0, stream>>>(kw, bw);

    if (ws_size >= BW_BYTES + PAD_BYTES) {
        unsigned short* xp = (unsigned short*)((char*)d_ws + BW_BYTES);
        pad_kernel<<<(int)((PADELEMS / 8 + 255) / 256), 256, 0, stream>>>(x, xp);
        conv7_kernel<<<MTOT / 256, 512, 0, stream>>>(xp, bw, out);
    } else {
        dim3 grid(MTOT / 128, COUT / 128);
        conv_fallback_kernel<<<grid, 256, 0, stream>>>(x, bw, out);
    }
}

// Round 8
// 396.114 us; speedup vs baseline: 1.2954x; 1.2954x over previous
//
#include <hip/hip_runtime.h>

typedef __attribute__((ext_vector_type(8))) short short8;
typedef __attribute__((ext_vector_type(4))) float f32x4;
typedef __attribute__((ext_vector_type(4))) unsigned short u16x4;
typedef __attribute__((ext_vector_type(8))) unsigned short u16x8;

#define H 112
#define W 112
#define HP 114
#define WP 114
#define CIN 128
#define COUT 256
#define NPIX (H * W)          // 12544
#define NIMG 32
#define MTOT (NIMG * NPIX)    // 401408
#define PADELEMS ((long)NIMG * HP * WP * CIN)  // 53,231,616
#define NSTEP 36              // K-steps: 9 taps x 4 cin-chunks of 32

__device__ __forceinline__ unsigned short f2bf(float f) {
    unsigned int u = __builtin_bit_cast(unsigned int, f);
    u += 0x7FFFu + ((u >> 16) & 1u);
    return (unsigned short)(u >> 16);
}

__device__ __forceinline__ void gl2lds16(const void* g, void* l) {
    __builtin_amdgcn_global_load_lds(
        (const __attribute__((address_space(1))) unsigned int*)g,
        (__attribute__((address_space(3))) unsigned int*)l,
        16, 0, 0);
}

// ---- weights bf16 {+1,-1}, layout [tap][kc4][kq4][cout256][e8] ----
// idx = ((((tap*4+kc)*4)+q)*256 + cout)*8 + e ; cin = kc*32 + q*8 + e
__global__ void binw3_kernel(const float* __restrict__ kw, unsigned short* __restrict__ bw) {
    int tid = blockIdx.x * 256 + threadIdx.x;
    int e    = tid & 7;
    int cout = (tid >> 3) & 255;
    int q    = (tid >> 11) & 3;
    int kc   = (tid >> 13) & 3;
    int tap  = tid >> 15;
    int cin  = kc * 32 + q * 8 + e;
    float w = kw[(tap * 128 + cin) * 256 + cout];
    bw[tid] = (w >= 0.0f) ? (unsigned short)0x3F80u : (unsigned short)0xBF80u;
}

// ---- x (f32 NHWC) -> zero-padded bf16 [N][114][114][128] ----
__global__ void pad_kernel(const float* __restrict__ x, unsigned short* __restrict__ xp) {
    long tid = (long)blockIdx.x * 256 + threadIdx.x;   // one thread = 8 elems
    if (tid >= PADELEMS / 8) return;
    int c8 = (int)(tid & 15);
    long rem = tid >> 4;
    int wp = (int)(rem % WP); rem /= WP;
    int hp = (int)(rem % HP);
    int n  = (int)(rem / HP);
    u16x8 v = {0, 0, 0, 0, 0, 0, 0, 0};
    if (hp >= 1 && hp <= H && wp >= 1 && wp <= W) {
        const float* s = x + (((long)(n * H + hp - 1) * W + (wp - 1)) * CIN + c8 * 8);
        f32x4 a = *(const f32x4*)s;
        f32x4 b = *(const f32x4*)(s + 4);
        v = (u16x8){ f2bf(a.x), f2bf(a.y), f2bf(a.z), f2bf(a.w),
                     f2bf(b.x), f2bf(b.y), f2bf(b.z), f2bf(b.w) };
    }
    *(u16x8*)(xp + tid * 8) = v;
}

// ---- 128x128 implicit GEMM, BK=32, 32KiB dbuf LDS, 4+ blocks/CU ----
// 4 waves (2x2), per-wave 64x64. Plane-major LDS: [buf][kq4][row128][8 shorts].
// TLP-first: small barrier domains, counted vmcnt, 2 barriers/step.
__global__ __launch_bounds__(256, 4)
void conv8_kernel(const unsigned short* __restrict__ xp, const unsigned short* __restrict__ bw,
                  float* __restrict__ out) {
    __shared__ unsigned short As[2][4096];  // 2 x 8KB
    __shared__ unsigned short Bs[2][4096];  // 2 x 8KB

    const int tid = threadIdx.x;
    const int swz = (blockIdx.x & 7) * 784 + (blockIdx.x >> 3);  // 6272 = 8*784, bijective
    const int bm = swz >> 1;       // consecutive swz pairs share bm (same XCD)
    const int bn = swz & 1;
    const int lane = tid & 63;
    const int wv = tid >> 6;
    const int wr = wv >> 1, wc = wv & 1;
    const int l15 = lane & 15;

    // staging: slot s=tid -> (plane q=tid>>7, row=tid&127); slot tid+256 -> plane q+2
    const int srow = tid & 127;
    const int sq = tid >> 7;       // 0/1
    {
        int p = bm * 128 + srow;
        int n0 = p / NPIX;
        int rem0 = p - n0 * NPIX;
        int oh0 = rem0 / W, ow0 = rem0 - oh0 * W;
        // nothing else
        (void)oh0; (void)ow0;
    }
    int p0 = bm * 128 + srow;
    int n0 = p0 / NPIX;
    int rem0 = p0 - n0 * NPIX;
    int oh0 = rem0 / W, ow0 = rem0 - oh0 * W;
    const unsigned short* aptr = xp + (long)((n0 * HP + oh0 + 1) * WP + ow0 + 1) * CIN + sq * 8;
    const unsigned short* bptr = bw + (bn * 128 + srow) * 8 + sq * 2048;

    // A: pixel srow, cin chunk kc*32 + q*8 (q=sq and sq+2 -> +16 shorts)
#define STAGE(T, BUF) do {                                                      \
        const int _tap = (T) >> 2, _kc = (T) & 3;                               \
        const long _sh = (long)((_tap / 3 - 1) * WP + (_tap % 3 - 1)) * CIN     \
                         + _kc * 32;                                            \
        gl2lds16(aptr + _sh,      &As[BUF][tid * 8]);                           \
        gl2lds16(aptr + _sh + 16, &As[BUF][tid * 8 + 2048]);                    \
        gl2lds16(bptr + (T) * 8192,        &Bs[BUF][tid * 8]);                  \
        gl2lds16(bptr + (T) * 8192 + 4096, &Bs[BUF][tid * 8 + 2048]);           \
    } while (0)

    // frag reads: lane l -> plane l>>4, row base + l15; 16 lanes = 256B contiguous
    const int aoff = (lane >> 4) * 1024 + (wr * 64 + l15) * 8;   // + m*128
    const int boff = (lane >> 4) * 1024 + (wc * 64 + l15) * 8;   // + n*128

    f32x4 acc[4][4];
#pragma unroll
    for (int m = 0; m < 4; ++m)
#pragma unroll
        for (int n = 0; n < 4; ++n)
            acc[m][n] = (f32x4){0.f, 0.f, 0.f, 0.f};

    STAGE(0, 0);   // prologue: step 0 in flight (4 loads)

#pragma unroll
    for (int t = 0; t < NSTEP; ++t) {
        const int buf = t & 1;
        if (t < NSTEP - 1) {
            STAGE(t + 1, buf ^ 1);
            asm volatile("s_waitcnt vmcnt(4)" ::: "memory");  // step t resident
        } else {
            asm volatile("s_waitcnt vmcnt(0)" ::: "memory");
        }
        __builtin_amdgcn_s_barrier();

        short8 afr[4], bfr[4];
#pragma unroll
        for (int n = 0; n < 4; ++n)
            bfr[n] = *(const short8*)&Bs[buf][boff + n * 128];
#pragma unroll
        for (int m = 0; m < 4; ++m)
            afr[m] = *(const short8*)&As[buf][aoff + m * 128];
        asm volatile("s_waitcnt lgkmcnt(0)" ::: "memory");
        __builtin_amdgcn_sched_barrier(0);
        __builtin_amdgcn_s_setprio(1);
#pragma unroll
        for (int m = 0; m < 4; ++m)
#pragma unroll
            for (int n = 0; n < 4; ++n)
                acc[m][n] = __builtin_amdgcn_mfma_f32_16x16x32_bf16(
                    afr[m], bfr[n], acc[m][n], 0, 0, 0);
        __builtin_amdgcn_s_setprio(0);
        __builtin_amdgcn_s_barrier();
    }
#undef STAGE

    // ---- epilogue: C/D layout col=lane&15, row=(lane>>4)*4+j ----
    const long row0 = (long)bm * 128 + wr * 64 + (lane >> 4) * 4;
    const int col = bn * 128 + wc * 64 + l15;
#pragma unroll
    for (int m = 0; m < 4; ++m)
#pragma unroll
        for (int n = 0; n < 4; ++n)
#pragma unroll
            for (int j = 0; j < 4; ++j)
                out[(row0 + m * 16 + j) * COUT + col + n * 16] = acc[m][n][j];
}

// ---------------- fallback (round-1) path: needs no big workspace ----------------
__global__ void binw_kernel(const float* __restrict__ kw, unsigned short* __restrict__ bw) {
    int tid = blockIdx.x * 256 + threadIdx.x;
    int cin5 = tid & 31;
    int cout = (tid >> 5) & 255;
    int kc4  = (tid >> 13) & 3;
    int tap  = tid >> 15;
    int cin  = kc4 * 32 + cin5;
    float w = kw[(tap * 128 + cin) * 256 + cout];
    bw[tid] = (w >= 0.0f) ? (unsigned short)0x3F80u : (unsigned short)0xBF80u;
}

__global__ __launch_bounds__(256, 2)
void conv_fallback_kernel(const float* __restrict__ x, const unsigned short* __restrict__ bw,
                          float* __restrict__ out) {
    __shared__ unsigned short As[128][40];
    __shared__ unsigned short Bs[128][40];
    const int tid = threadIdx.x;
    const int bm = blockIdx.x, bn = blockIdx.y;
    const int lane = tid & 63;
    const int wv = tid >> 6;
    const int wr = wv >> 1, wc = wv & 1;
    const int c4 = (tid & 7) * 4;
    const int rseg = tid >> 3;
    int ohs[4], ows[4], bases[4];
#pragma unroll
    for (int i = 0; i < 4; ++i) {
        int p = bm * 128 + rseg + i * 32;
        int n = p / NPIX;
        int rem = p - n * NPIX;
        int oh = rem / W, ow = rem - oh * W;
        ohs[i] = oh; ows[i] = ow;
        bases[i] = ((n * H + oh) * W + ow) * CIN;
    }
    f32x4 acc[4][4];
#pragma unroll
    for (int m = 0; m < 4; ++m)
#pragma unroll
        for (int n = 0; n < 4; ++n)
            acc[m][n] = (f32x4){0.f, 0.f, 0.f, 0.f};
    const int arow = wr * 64 + (lane & 15);
    const int brow = wc * 64 + (lane & 15);
    const int koff = (lane >> 4) * 8;
    for (int tap = 0; tap < 9; ++tap) {
        const int dh = tap / 3 - 1, dw = tap % 3 - 1;
        const int shift = (dh * W + dw) * CIN;
#pragma unroll
        for (int kc = 0; kc < 4; ++kc) {
            __syncthreads();
#pragma unroll
            for (int i = 0; i < 4; ++i) {
                int ih = ohs[i] + dh, iw = ows[i] + dw;
                bool valid = ((unsigned)ih < (unsigned)H) & ((unsigned)iw < (unsigned)W);
                f32x4 v = {0.f, 0.f, 0.f, 0.f};
                if (valid) v = *(const f32x4*)(x + bases[i] + shift + kc * 32 + c4);
                u16x4 s = { f2bf(v.x), f2bf(v.y), f2bf(v.z), f2bf(v.w) };
                *(u16x4*)&As[rseg + i * 32][c4] = s;
            }
            const unsigned short* bp = bw + tap * 32768 + kc * 8192 + bn * 4096;
#pragma unroll
            for (int j = 0; j < 2; ++j) {
                int idx = tid + j * 256;
                *(u16x8*)&Bs[idx >> 2][(idx & 3) * 8] = *(const u16x8*)(bp + (idx >> 2) * 32 + (idx & 3) * 8);
            }
            __syncthreads();
            short8 af[4], bfr[4];
#pragma unroll
            for (int m = 0; m < 4; ++m)
                af[m] = *(const short8*)&As[arow + m * 16][koff];
#pragma unroll
            for (int n = 0; n < 4; ++n)
                bfr[n] = *(const short8*)&Bs[brow + n * 16][koff];
#pragma unroll
            for (int m = 0; m < 4; ++m)
#pragma unroll
                for (int n = 0; n < 4; ++n)
                    acc[m][n] = __builtin_amdgcn_mfma_f32_16x16x32_bf16(af[m], bfr[n], acc[m][n], 0, 0, 0);
        }
    }
    const long row0 = (long)bm * 128 + wr * 64 + ((lane >> 4) * 4);
    const int col = bn * 128 + wc * 64 + (lane & 15);
#pragma unroll
    for (int m = 0; m < 4; ++m)
#pragma unroll
        for (int n = 0; n < 4; ++n)
#pragma unroll
            for (int j = 0; j < 4; ++j)
                out[(row0 + m * 16 + j) * COUT + col + n * 16] = acc[m][n][j];
}

extern "C" void kernel_launch(void* const* d_in, const int* in_sizes, int n_in,
                              void* d_out, int out_size, void* d_ws, size_t ws_size,
                              hipStream_t stream) {
    const float* x  = (const float*)d_in[0];
    const float* kw = (const float*)d_in[1];
    float* out = (float*)d_out;
    unsigned short* bw = (unsigned short*)d_ws;
    const size_t BW_BYTES = 9 * 4 * 4 * 256 * 8 * 2;      // 589,824
    const size_t PAD_BYTES = (size_t)PADELEMS * 2;        // ~106.5 MB

    if (ws_size >= BW_BYTES + PAD_BYTES) {
        binw3_kernel<<<(9 * 4 * 4 * 256 * 8) / 256, 256, 0, stream>>>(kw, bw);
        unsigned short* xp = (unsigned short*)((char*)d_ws + BW_BYTES);
        pad_kernel<<<(int)((PADELEMS / 8 + 255) / 256), 256, 0, stream>>>(x, xp);
        conv8_kernel<<<(MTOT / 128) * 2, 256, 0, stream>>>(xp, bw, out);
    } else {
        binw_kernel<<<(9 * 256 * 128) / 256, 256, 0, stream>>>(kw, bw);
        dim3 grid(MTOT / 128, COUT / 128);
        conv_fallback_kernel<<<grid, 256, 0, stream>>>(x, bw, out);
    }
}